// Round 11
// baseline (147.324 us; speedup 1.0000x reference)
//
#include <hip/hip_runtime.h>

#define IN_DIM 128
#define HC     256      // H*C
#define CCH    64
#define NH     4
#define NEG    0.2f
#define SLOT   64       // per-dst edge slot capacity (Poisson(16), max deg ~45)

typedef __attribute__((ext_vector_type(4))) float f32x4;
typedef __attribute__((ext_vector_type(8))) short short8;

static __device__ __forceinline__ unsigned short f2bf(float f) {
  unsigned int u = __float_as_uint(f);
  u = (u + 0x7fffu + ((u >> 16) & 1u)) >> 16;   // RNE
  return (unsigned short)u;
}
static __device__ __forceinline__ float bf_lo(unsigned int u) {
  return __uint_as_float(u << 16);
}
static __device__ __forceinline__ float bf_hi(unsigned int u) {
  return __uint_as_float(u & 0xffff0000u);
}

// ---- K1: fused rel_attn (block 0) + scatter (1..SB, dispatched early) + gemm (rest) ----
__global__ __launch_bounds__(256) void fused_k(
    const float* __restrict__ x, const float* __restrict__ W,
    const float* __restrict__ att_src, const float* __restrict__ att_dst,
    const float* __restrict__ rel_emb, const float* __restrict__ W_edge,
    const float* __restrict__ att_edge,
    const int* __restrict__ src, const int* __restrict__ dst,
    const int* __restrict__ et, int* __restrict__ counts,
    unsigned int* __restrict__ packed,
    unsigned short* __restrict__ xpb, float* __restrict__ a_srcv,
    float* __restrict__ a_dstv, float* __restrict__ a_rel,
    int Nn, int E, int R, int SB) {
  __shared__ unsigned short Asm[64][136];   // 17.4 KB
  __shared__ unsigned short Bsm[64][136];   // 17.4 KB (reused as Xb[64][70] per head)
  const int bid = blockIdx.x;
  const int tid = threadIdx.x;

  if (bid == 0) {
    // rel_attn: a_rel[r,h] = rel_emb[r,:] . v[h,:], v[h,k]=sum_c ae[h,c]*W_edge[h*64+c,k]
    float* v = (float*)&Asm[0][0];  // 512 floats
    for (int t = tid; t < NH * IN_DIM; t += 256) {
      int h = t >> 7, k = t & 127;
      const float* base = W_edge + (size_t)h * CCH * IN_DIM + k;
      const float* ae = att_edge + h * CCH;
      float s = 0.f;
#pragma unroll 8
      for (int c = 0; c < CCH; ++c) s += ae[c] * base[(size_t)c * IN_DIM];
      v[t] = s;
    }
    __syncthreads();
    if (tid < R * NH) {
      int r = tid >> 2, h = tid & 3;
      const float4* re = (const float4*)(rel_emb + (size_t)r * IN_DIM);
      const float4* vv = (const float4*)(v + h * IN_DIM);
      float s = 0.f;
#pragma unroll 8
      for (int k = 0; k < IN_DIM / 4; ++k) {
        float4 a = re[k], b = vv[k];
        s += a.x * b.x + a.y * b.y + a.z * b.z + a.w * b.w;
      }
      a_rel[tid] = s;
    }
    return;
  }

  if (bid <= SB) {
    // direct scatter: packed[d*SLOT + pos] = (etype<<26 | src)
    for (int e = (bid - 1) * 256 + tid; e < E; e += SB * 256) {
      int d = dst[e];
      unsigned int pk = ((unsigned int)et[e] << 26) | (unsigned int)src[e];
      int pos = atomicAdd(&counts[d], 1);
      if (pos < SLOT) packed[(size_t)d * SLOT + pos] = pk;
    }
    return;
  }

  // ----- gemm: BM=64 rows, heads looped in-block
  const int bm = (bid - SB - 1) * 64;
  {
    int row = tid >> 2, q = (tid & 3) * 32;
    int gm = bm + row;
    if (gm < Nn) {
      const float* xr = x + (size_t)gm * IN_DIM + q;
#pragma unroll
      for (int i = 0; i < 32; i += 8) {
        float4 a = *(const float4*)(xr + i);
        float4 b = *(const float4*)(xr + i + 4);
        ushort4 u0, u1;
        u0.x = f2bf(a.x); u0.y = f2bf(a.y); u0.z = f2bf(a.z); u0.w = f2bf(a.w);
        u1.x = f2bf(b.x); u1.y = f2bf(b.y); u1.z = f2bf(b.z); u1.w = f2bf(b.w);
        *(ushort4*)&Asm[row][q + i]     = u0;
        *(ushort4*)&Asm[row][q + i + 4] = u1;
      }
    } else {
      ushort4 zz = {0, 0, 0, 0};
#pragma unroll
      for (int i = 0; i < 32; i += 4) *(ushort4*)&Asm[row][q + i] = zz;
    }
  }

  const int wv = tid >> 6, lane = tid & 63;
  const int lr = lane & 15, lk = lane >> 4;
  unsigned short* Xb = (unsigned short*)&Bsm[0][0];   // [64][70] bf16 transpose buffer

  for (int h = 0; h < NH; ++h) {
    __syncthreads();   // prev head's Xb reads done (h=0: A staged)
    {
      int row = tid >> 2, q = (tid & 3) * 32;
      const float* wr = W + (size_t)(h * CCH + row) * IN_DIM + q;
#pragma unroll
      for (int i = 0; i < 32; i += 8) {
        float4 a = *(const float4*)(wr + i);
        float4 b = *(const float4*)(wr + i + 4);
        ushort4 u0, u1;
        u0.x = f2bf(a.x); u0.y = f2bf(a.y); u0.z = f2bf(a.z); u0.w = f2bf(a.w);
        u1.x = f2bf(b.x); u1.y = f2bf(b.y); u1.z = f2bf(b.z); u1.w = f2bf(b.w);
        *(ushort4*)&Bsm[row][q + i]     = u0;
        *(ushort4*)&Bsm[row][q + i + 4] = u1;
      }
    }
    __syncthreads();

    f32x4 acc[4] = {};
#pragma unroll
    for (int kk = 0; kk < 4; ++kk) {
      const int ko = kk * 32 + lk * 8;
      short8 af = *(const short8*)&Asm[wv * 16 + lr][ko];
      short8 b0 = *(const short8*)&Bsm[lr][ko];
      short8 b1 = *(const short8*)&Bsm[16 + lr][ko];
      short8 b2 = *(const short8*)&Bsm[32 + lr][ko];
      short8 b3 = *(const short8*)&Bsm[48 + lr][ko];
      acc[0] = __builtin_amdgcn_mfma_f32_16x16x32_bf16(af, b0, acc[0], 0, 0, 0);
      acc[1] = __builtin_amdgcn_mfma_f32_16x16x32_bf16(af, b1, acc[1], 0, 0, 0);
      acc[2] = __builtin_amdgcn_mfma_f32_16x16x32_bf16(af, b2, acc[2], 0, 0, 0);
      acc[3] = __builtin_amdgcn_mfma_f32_16x16x32_bf16(af, b3, acc[3], 0, 0, 0);
    }

    __syncthreads();   // all waves done reading Bsm -> safe to overwrite as Xb

    // transpose acc -> Xb[64][70] bf16 (stride 70: conflict-free write & ~2-way read)
#pragma unroll
    for (int ni = 0; ni < 4; ++ni)
#pragma unroll
      for (int r = 0; r < 4; ++r)
        Xb[(wv * 16 + lk * 4 + r) * 70 + ni * 16 + lr] = f2bf(acc[ni][r]);

    // a_src/a_dst reduction (register-only, overlaps LDS latency)
    float as4[4], ad4[4];
#pragma unroll
    for (int ni = 0; ni < 4; ++ni) {
      as4[ni] = att_src[h * CCH + ni * 16 + lr];
      ad4[ni] = att_dst[h * CCH + ni * 16 + lr];
    }
#pragma unroll
    for (int r = 0; r < 4; ++r) {
      int gm = bm + wv * 16 + lk * 4 + r;
      float ps = 0.f, pd = 0.f;
#pragma unroll
      for (int ni = 0; ni < 4; ++ni) {
        ps += acc[ni][r] * as4[ni];
        pd += acc[ni][r] * ad4[ni];
      }
      ps += __shfl_xor(ps, 1); pd += __shfl_xor(pd, 1);
      ps += __shfl_xor(ps, 2); pd += __shfl_xor(pd, 2);
      ps += __shfl_xor(ps, 4); pd += __shfl_xor(pd, 4);
      ps += __shfl_xor(ps, 8); pd += __shfl_xor(pd, 8);
      if (lr == 0 && gm < Nn) {
        a_srcv[(size_t)gm * NH + h] = ps;
        a_dstv[(size_t)gm * NH + h] = pd;
      }
    }

    __syncthreads();   // transpose writes visible

    // wide coalesced xpb store: each thread stores one 16-col quarter-row (32 B)
    {
      int row = tid >> 2, q = tid & 3;
      int gm = bm + row;
      if (gm < Nn) {
        const unsigned int* xu = (const unsigned int*)(Xb + row * 70 + q * 16);
        uint4 o0, o1;
        o0.x = xu[0]; o0.y = xu[1]; o0.z = xu[2]; o0.w = xu[3];
        o1.x = xu[4]; o1.y = xu[5]; o1.z = xu[6]; o1.w = xu[7];
        uint4* dp = (uint4*)(xpb + (size_t)gm * HC + h * CCH + q * 16);
        dp[0] = o0; dp[1] = o1;
      }
    }
  }
}

// ---- K2: one wave per dst; 32 lanes x 16B per edge row, 2 edges/iter ----
__global__ void gat_out_k(const int* __restrict__ counts,
                          const unsigned int* __restrict__ packed,
                          const float* __restrict__ a_srcv, const float* __restrict__ a_dstv,
                          const float* __restrict__ a_rel, int R,
                          const unsigned short* __restrict__ xpb,
                          const float* __restrict__ bias,
                          float* __restrict__ out, int Nn) {
  __shared__ float arl[NH * 64];
  int tid = threadIdx.x;
  if (tid < R * NH) arl[tid] = a_rel[tid];
  __syncthreads();
  int d = blockIdx.x * 4 + (tid >> 6);
  if (d >= Nn) return;
  int lane = tid & 63;
  int half = lane >> 5, l32 = lane & 31;
  int hl = l32 >> 3;                 // head owned by this lane
  const int choff = l32 * 8;         // channels choff..choff+7 (global 0..255)
  int cnt = counts[d];
  if (cnt > SLOT) cnt = SLOT;
  int beg = d * SLOT, end = beg + cnt;
  float ad = a_dstv[(size_t)d * NH + hl];
  float z = 0.f;
  float acc[8] = {0.f, 0.f, 0.f, 0.f, 0.f, 0.f, 0.f, 0.f};

  int j = beg;
  for (; j + 4 <= end; j += 4) {
    unsigned int pkA = packed[j + half];
    unsigned int pkB = packed[j + 2 + half];
    int sA = (int)(pkA & 0x03FFFFFFu), tA = (int)(pkA >> 26);
    int sB = (int)(pkB & 0x03FFFFFFu), tB = (int)(pkB >> 26);
    float alA = a_srcv[(size_t)sA * NH + hl] + ad + arl[tA * NH + hl];
    float alB = a_srcv[(size_t)sB * NH + hl] + ad + arl[tB * NH + hl];
    uint4 uA = *(const uint4*)(xpb + (size_t)sA * HC + choff);
    uint4 uB = *(const uint4*)(xpb + (size_t)sB * HC + choff);
    alA = fmaxf(alA, NEG * alA);
    alB = fmaxf(alB, NEG * alB);
    float wA = __expf(alA), wB = __expf(alB);
    z += wA + wB;
    acc[0] += wA * bf_lo(uA.x) + wB * bf_lo(uB.x);
    acc[1] += wA * bf_hi(uA.x) + wB * bf_hi(uB.x);
    acc[2] += wA * bf_lo(uA.y) + wB * bf_lo(uB.y);
    acc[3] += wA * bf_hi(uA.y) + wB * bf_hi(uB.y);
    acc[4] += wA * bf_lo(uA.z) + wB * bf_lo(uB.z);
    acc[5] += wA * bf_hi(uA.z) + wB * bf_hi(uB.z);
    acc[6] += wA * bf_lo(uA.w) + wB * bf_lo(uB.w);
    acc[7] += wA * bf_hi(uA.w) + wB * bf_hi(uB.w);
  }
  for (; j < end; j += 2) {
    int e = j + half;
    bool valid = (e < end);
    int es = valid ? e : beg;
    unsigned int pk = packed[es];
    int s = (int)(pk & 0x03FFFFFFu), t = (int)(pk >> 26);
    float al = a_srcv[(size_t)s * NH + hl] + ad + arl[t * NH + hl];
    al = fmaxf(al, NEG * al);
    float w = valid ? __expf(al) : 0.f;
    uint4 u = *(const uint4*)(xpb + (size_t)s * HC + choff);
    z += w;
    acc[0] += w * bf_lo(u.x);
    acc[1] += w * bf_hi(u.x);
    acc[2] += w * bf_lo(u.y);
    acc[3] += w * bf_hi(u.y);
    acc[4] += w * bf_lo(u.z);
    acc[5] += w * bf_hi(u.z);
    acc[6] += w * bf_lo(u.w);
    acc[7] += w * bf_hi(u.w);
  }

  // combine the two halves (edge parity)
  z += __shfl_xor(z, 32);
#pragma unroll
  for (int q = 0; q < 8; ++q) acc[q] += __shfl_xor(acc[q], 32);
  float inv = 0.25f / (z + 1e-16f);
#pragma unroll
  for (int q = 0; q < 8; ++q) acc[q] *= inv;
  // head mean: sum lanes {l32, l32^8, l32^16, l32^24}
#pragma unroll
  for (int q = 0; q < 8; ++q) {
    acc[q] += __shfl_xor(acc[q], 8);
    acc[q] += __shfl_xor(acc[q], 16);
  }
  if (lane < 8) {
    int c0 = lane * 8;
    const float4 b0 = *(const float4*)(bias + c0);
    const float4 b1 = *(const float4*)(bias + c0 + 4);
    float4 o0, o1;
    o0.x = acc[0] + b0.x; o0.y = acc[1] + b0.y; o0.z = acc[2] + b0.z; o0.w = acc[3] + b0.w;
    o1.x = acc[4] + b1.x; o1.y = acc[5] + b1.y; o1.z = acc[6] + b1.z; o1.w = acc[7] + b1.w;
    *(float4*)(out + (size_t)d * CCH + c0) = o0;
    *(float4*)(out + (size_t)d * CCH + c0 + 4) = o1;
  }
}

extern "C" void kernel_launch(void* const* d_in, const int* in_sizes, int n_in,
                              void* d_out, int out_size, void* d_ws, size_t ws_size,
                              hipStream_t stream) {
  const float* x        = (const float*)d_in[0];
  const int*   eidx     = (const int*)d_in[1];
  const int*   etype    = (const int*)d_in[2];
  const float* rel_emb  = (const float*)d_in[3];
  const float* W        = (const float*)d_in[4];
  const float* att_src  = (const float*)d_in[5];
  const float* att_dst  = (const float*)d_in[6];
  const float* W_edge   = (const float*)d_in[7];
  const float* att_edge = (const float*)d_in[8];
  const float* bias     = (const float*)d_in[9];
  float* out = (float*)d_out;

  const int Nn = in_sizes[0] / IN_DIM;
  const int E  = in_sizes[1] / 2;
  const int R  = in_sizes[3] / IN_DIM;
  const int* src = eidx;
  const int* dst = eidx + E;

  char* ws = (char*)d_ws;
  size_t off = 0;
  auto alloc = [&](size_t bytes) {
    void* p = ws + off;
    off = (off + bytes + 255) & ~(size_t)255;
    return p;
  };
  unsigned short* xpb = (unsigned short*)alloc((size_t)Nn * HC * 2);
  float* a_srcv = (float*)alloc((size_t)Nn * NH * 4);
  float* a_dstv = (float*)alloc((size_t)Nn * NH * 4);
  float* a_rel  = (float*)alloc((size_t)R * NH * 4);
  int*   counts = (int*)alloc((size_t)Nn * 4);
  unsigned int* packed = (unsigned int*)alloc((size_t)Nn * SLOT * 4);

  const int GB = (Nn + 63) / 64;      // gemm blocks
  const int SB = 512;                 // scatter blocks (dispatched before gemm)

  hipMemsetAsync(counts, 0, (size_t)Nn * 4, stream);

  hipLaunchKernelGGL(fused_k, dim3(1 + SB + GB), dim3(256), 0, stream,
                     x, W, att_src, att_dst, rel_emb, W_edge, att_edge,
                     src, dst, etype, counts, packed,
                     xpb, a_srcv, a_dstv, a_rel, Nn, E, R, SB);
  hipLaunchKernelGGL(gat_out_k, dim3((Nn + 3) / 4), dim3(256), 0, stream,
                     counts, packed, a_srcv, a_dstv, a_rel, R, xpb, bias, out, Nn);
}

// Round 12
// 140.389 us; speedup vs baseline: 1.0494x; 1.0494x over previous
//
#include <hip/hip_runtime.h>

#define IN_DIM 128
#define HC     256      // H*C
#define CCH    64
#define NH     4
#define NEG    0.2f
#define SLOT   64       // per-dst edge slot capacity (Poisson(16), max deg ~45)

typedef __attribute__((ext_vector_type(4))) float f32x4;
typedef __attribute__((ext_vector_type(8))) short short8;

static __device__ __forceinline__ unsigned short f2bf(float f) {
  unsigned int u = __float_as_uint(f);
  u = (u + 0x7fffu + ((u >> 16) & 1u)) >> 16;   // RNE
  return (unsigned short)u;
}
static __device__ __forceinline__ float bf_lo(unsigned int u) {
  return __uint_as_float(u << 16);
}
static __device__ __forceinline__ float bf_hi(unsigned int u) {
  return __uint_as_float(u & 0xffff0000u);
}

// ---- K1: fused rel_attn (block 0) + gemm (1..GB) + scatter (rest), 512 threads ----
__global__ __launch_bounds__(512) void fused_k(
    const float* __restrict__ x, const float* __restrict__ W,
    const float* __restrict__ att_src, const float* __restrict__ att_dst,
    const float* __restrict__ rel_emb, const float* __restrict__ W_edge,
    const float* __restrict__ att_edge,
    const int* __restrict__ src, const int* __restrict__ dst,
    const int* __restrict__ et, int* __restrict__ counts,
    unsigned int* __restrict__ packed,
    unsigned short* __restrict__ xpb, float* __restrict__ a_srcv,
    float* __restrict__ a_dstv, float* __restrict__ a_rel,
    int Nn, int E, int R, int GB, int SB) {
  __shared__ unsigned short Asm[128][136];  // 34.8 KB
  __shared__ unsigned short Bsm[64][136];   // 17.4 KB (reused as Xb[128][68] per head)
  const int bid = blockIdx.x;
  const int tid = threadIdx.x;

  if (bid == 0) {
    // rel_attn: a_rel[r,h] = rel_emb[r,:] . v[h,:], v[h,k]=sum_c ae[h,c]*W_edge[h*64+c,k]
    float* v = (float*)&Asm[0][0];  // 512 floats
    {
      int h = tid >> 7, k = tid & 127;
      const float* base = W_edge + (size_t)h * CCH * IN_DIM + k;
      const float* ae = att_edge + h * CCH;
      float s = 0.f;
#pragma unroll 8
      for (int c = 0; c < CCH; ++c) s += ae[c] * base[(size_t)c * IN_DIM];
      v[tid] = s;
    }
    __syncthreads();
    if (tid < R * NH) {
      int r = tid >> 2, h = tid & 3;
      const float4* re = (const float4*)(rel_emb + (size_t)r * IN_DIM);
      const float4* vv = (const float4*)(v + h * IN_DIM);
      float s = 0.f;
#pragma unroll 8
      for (int k = 0; k < IN_DIM / 4; ++k) {
        float4 a = re[k], b = vv[k];
        s += a.x * b.x + a.y * b.y + a.z * b.z + a.w * b.w;
      }
      a_rel[tid] = s;
    }
    return;
  }

  if (bid > GB) {
    // direct scatter: packed[d*SLOT + pos] = (etype<<26 | src)
    for (int e = (bid - GB - 1) * 512 + tid; e < E; e += SB * 512) {
      int d = dst[e];
      unsigned int pk = ((unsigned int)et[e] << 26) | (unsigned int)src[e];
      int pos = atomicAdd(&counts[d], 1);
      if (pos < SLOT) packed[(size_t)d * SLOT + pos] = pk;
    }
    return;
  }

  // ----- gemm: BM=128 rows, heads looped in-block, 8 waves
  const int bm = (bid - 1) * 128;
  {
    int row = tid >> 2, q = (tid & 3) * 32;
    int gm = bm + row;
    if (gm < Nn) {
      const float* xr = x + (size_t)gm * IN_DIM + q;
#pragma unroll
      for (int i = 0; i < 32; i += 8) {
        float4 a = *(const float4*)(xr + i);
        float4 b = *(const float4*)(xr + i + 4);
        ushort4 u0, u1;
        u0.x = f2bf(a.x); u0.y = f2bf(a.y); u0.z = f2bf(a.z); u0.w = f2bf(a.w);
        u1.x = f2bf(b.x); u1.y = f2bf(b.y); u1.z = f2bf(b.z); u1.w = f2bf(b.w);
        *(ushort4*)&Asm[row][q + i]     = u0;
        *(ushort4*)&Asm[row][q + i + 4] = u1;
      }
    } else {
      ushort4 zz = {0, 0, 0, 0};
#pragma unroll
      for (int i = 0; i < 32; i += 4) *(ushort4*)&Asm[row][q + i] = zz;
    }
  }

  const int wv = tid >> 6, lane = tid & 63;
  const int lr = lane & 15, lk = lane >> 4;
  unsigned short* Xb = (unsigned short*)&Bsm[0][0];   // [128][68] bf16 transpose buffer

  for (int h = 0; h < NH; ++h) {
    __syncthreads();   // prev head's Xb reads done (h=0: A staged)
    {
      int row = tid >> 3, q = (tid & 7) * 16;
      const float* wr = W + (size_t)(h * CCH + row) * IN_DIM + q;
#pragma unroll
      for (int i = 0; i < 16; i += 8) {
        float4 a = *(const float4*)(wr + i);
        float4 b = *(const float4*)(wr + i + 4);
        ushort4 u0, u1;
        u0.x = f2bf(a.x); u0.y = f2bf(a.y); u0.z = f2bf(a.z); u0.w = f2bf(a.w);
        u1.x = f2bf(b.x); u1.y = f2bf(b.y); u1.z = f2bf(b.z); u1.w = f2bf(b.w);
        *(ushort4*)&Bsm[row][q + i]     = u0;
        *(ushort4*)&Bsm[row][q + i + 4] = u1;
      }
    }
    __syncthreads();

    f32x4 acc[4] = {};
#pragma unroll
    for (int kk = 0; kk < 4; ++kk) {
      const int ko = kk * 32 + lk * 8;
      short8 af = *(const short8*)&Asm[wv * 16 + lr][ko];
      short8 b0 = *(const short8*)&Bsm[lr][ko];
      short8 b1 = *(const short8*)&Bsm[16 + lr][ko];
      short8 b2 = *(const short8*)&Bsm[32 + lr][ko];
      short8 b3 = *(const short8*)&Bsm[48 + lr][ko];
      acc[0] = __builtin_amdgcn_mfma_f32_16x16x32_bf16(af, b0, acc[0], 0, 0, 0);
      acc[1] = __builtin_amdgcn_mfma_f32_16x16x32_bf16(af, b1, acc[1], 0, 0, 0);
      acc[2] = __builtin_amdgcn_mfma_f32_16x16x32_bf16(af, b2, acc[2], 0, 0, 0);
      acc[3] = __builtin_amdgcn_mfma_f32_16x16x32_bf16(af, b3, acc[3], 0, 0, 0);
    }

    __syncthreads();   // all waves done reading Bsm (MFMA) -> safe to overwrite as Xb

    // transpose acc -> Xb[128][68] bf16
#pragma unroll
    for (int ni = 0; ni < 4; ++ni)
#pragma unroll
      for (int r = 0; r < 4; ++r)
        Xb[(wv * 16 + lk * 4 + r) * 68 + ni * 16 + lr] = f2bf(acc[ni][r]);

    // a_src/a_dst reduction (register-only, overlaps LDS latency)
    float as4[4], ad4[4];
#pragma unroll
    for (int ni = 0; ni < 4; ++ni) {
      as4[ni] = att_src[h * CCH + ni * 16 + lr];
      ad4[ni] = att_dst[h * CCH + ni * 16 + lr];
    }
#pragma unroll
    for (int r = 0; r < 4; ++r) {
      int gm = bm + wv * 16 + lk * 4 + r;
      float ps = 0.f, pd = 0.f;
#pragma unroll
      for (int ni = 0; ni < 4; ++ni) {
        ps += acc[ni][r] * as4[ni];
        pd += acc[ni][r] * ad4[ni];
      }
      ps += __shfl_xor(ps, 1); pd += __shfl_xor(pd, 1);
      ps += __shfl_xor(ps, 2); pd += __shfl_xor(pd, 2);
      ps += __shfl_xor(ps, 4); pd += __shfl_xor(pd, 4);
      ps += __shfl_xor(ps, 8); pd += __shfl_xor(pd, 8);
      if (lr == 0 && gm < Nn) {
        a_srcv[(size_t)gm * NH + h] = ps;
        a_dstv[(size_t)gm * NH + h] = pd;
      }
    }

    __syncthreads();   // transpose writes visible

    // coalesced xpb store: each thread stores one 16-col quarter-row (32 B)
    {
      int row = tid >> 2, q = tid & 3;
      int gm = bm + row;
      if (gm < Nn) {
        const unsigned int* xu = (const unsigned int*)(Xb + row * 68 + q * 16);
        uint4 o0, o1;
        o0.x = xu[0]; o0.y = xu[1]; o0.z = xu[2]; o0.w = xu[3];
        o1.x = xu[4]; o1.y = xu[5]; o1.z = xu[6]; o1.w = xu[7];
        uint4* dp = (uint4*)(xpb + (size_t)gm * HC + h * CCH + q * 16);
        dp[0] = o0; dp[1] = o1;
      }
    }
  }
}

// ---- K2: one wave per dst; 32 lanes x 16B per edge row, 2 edges/iter ----
__global__ void gat_out_k(const int* __restrict__ counts,
                          const unsigned int* __restrict__ packed,
                          const float* __restrict__ a_srcv, const float* __restrict__ a_dstv,
                          const float* __restrict__ a_rel, int R,
                          const unsigned short* __restrict__ xpb,
                          const float* __restrict__ bias,
                          float* __restrict__ out, int Nn) {
  __shared__ float arl[NH * 64];
  int tid = threadIdx.x;
  if (tid < R * NH) arl[tid] = a_rel[tid];
  __syncthreads();
  int d = blockIdx.x * 4 + (tid >> 6);
  if (d >= Nn) return;
  int lane = tid & 63;
  int half = lane >> 5, l32 = lane & 31;
  int hl = l32 >> 3;                 // head owned by this lane
  const int choff = l32 * 8;         // channels choff..choff+7 (global 0..255)
  int cnt = counts[d];
  if (cnt > SLOT) cnt = SLOT;
  int beg = d * SLOT, end = beg + cnt;
  float ad = a_dstv[(size_t)d * NH + hl];
  float z = 0.f;
  float acc[8] = {0.f, 0.f, 0.f, 0.f, 0.f, 0.f, 0.f, 0.f};

  int j = beg;
  for (; j + 4 <= end; j += 4) {
    unsigned int pkA = packed[j + half];
    unsigned int pkB = packed[j + 2 + half];
    int sA = (int)(pkA & 0x03FFFFFFu), tA = (int)(pkA >> 26);
    int sB = (int)(pkB & 0x03FFFFFFu), tB = (int)(pkB >> 26);
    float alA = a_srcv[(size_t)sA * NH + hl] + ad + arl[tA * NH + hl];
    float alB = a_srcv[(size_t)sB * NH + hl] + ad + arl[tB * NH + hl];
    uint4 uA = *(const uint4*)(xpb + (size_t)sA * HC + choff);
    uint4 uB = *(const uint4*)(xpb + (size_t)sB * HC + choff);
    alA = fmaxf(alA, NEG * alA);
    alB = fmaxf(alB, NEG * alB);
    float wA = __expf(alA), wB = __expf(alB);
    z += wA + wB;
    acc[0] += wA * bf_lo(uA.x) + wB * bf_lo(uB.x);
    acc[1] += wA * bf_hi(uA.x) + wB * bf_hi(uB.x);
    acc[2] += wA * bf_lo(uA.y) + wB * bf_lo(uB.y);
    acc[3] += wA * bf_hi(uA.y) + wB * bf_hi(uB.y);
    acc[4] += wA * bf_lo(uA.z) + wB * bf_lo(uB.z);
    acc[5] += wA * bf_hi(uA.z) + wB * bf_hi(uB.z);
    acc[6] += wA * bf_lo(uA.w) + wB * bf_lo(uB.w);
    acc[7] += wA * bf_hi(uA.w) + wB * bf_hi(uB.w);
  }
  for (; j < end; j += 2) {
    int e = j + half;
    bool valid = (e < end);
    int es = valid ? e : beg;
    unsigned int pk = packed[es];
    int s = (int)(pk & 0x03FFFFFFu), t = (int)(pk >> 26);
    float al = a_srcv[(size_t)s * NH + hl] + ad + arl[t * NH + hl];
    al = fmaxf(al, NEG * al);
    float w = valid ? __expf(al) : 0.f;
    uint4 u = *(const uint4*)(xpb + (size_t)s * HC + choff);
    z += w;
    acc[0] += w * bf_lo(u.x);
    acc[1] += w * bf_hi(u.x);
    acc[2] += w * bf_lo(u.y);
    acc[3] += w * bf_hi(u.y);
    acc[4] += w * bf_lo(u.z);
    acc[5] += w * bf_hi(u.z);
    acc[6] += w * bf_lo(u.w);
    acc[7] += w * bf_hi(u.w);
  }

  // combine the two halves (edge parity)
  z += __shfl_xor(z, 32);
#pragma unroll
  for (int q = 0; q < 8; ++q) acc[q] += __shfl_xor(acc[q], 32);
  float inv = 0.25f / (z + 1e-16f);
#pragma unroll
  for (int q = 0; q < 8; ++q) acc[q] *= inv;
  // head mean: sum lanes {l32, l32^8, l32^16, l32^24}
#pragma unroll
  for (int q = 0; q < 8; ++q) {
    acc[q] += __shfl_xor(acc[q], 8);
    acc[q] += __shfl_xor(acc[q], 16);
  }
  if (lane < 8) {
    int c0 = lane * 8;
    const float4 b0 = *(const float4*)(bias + c0);
    const float4 b1 = *(const float4*)(bias + c0 + 4);
    float4 o0, o1;
    o0.x = acc[0] + b0.x; o0.y = acc[1] + b0.y; o0.z = acc[2] + b0.z; o0.w = acc[3] + b0.w;
    o1.x = acc[4] + b1.x; o1.y = acc[5] + b1.y; o1.z = acc[6] + b1.z; o1.w = acc[7] + b1.w;
    *(float4*)(out + (size_t)d * CCH + c0) = o0;
    *(float4*)(out + (size_t)d * CCH + c0 + 4) = o1;
  }
}

extern "C" void kernel_launch(void* const* d_in, const int* in_sizes, int n_in,
                              void* d_out, int out_size, void* d_ws, size_t ws_size,
                              hipStream_t stream) {
  const float* x        = (const float*)d_in[0];
  const int*   eidx     = (const int*)d_in[1];
  const int*   etype    = (const int*)d_in[2];
  const float* rel_emb  = (const float*)d_in[3];
  const float* W        = (const float*)d_in[4];
  const float* att_src  = (const float*)d_in[5];
  const float* att_dst  = (const float*)d_in[6];
  const float* W_edge   = (const float*)d_in[7];
  const float* att_edge = (const float*)d_in[8];
  const float* bias     = (const float*)d_in[9];
  float* out = (float*)d_out;

  const int Nn = in_sizes[0] / IN_DIM;
  const int E  = in_sizes[1] / 2;
  const int R  = in_sizes[3] / IN_DIM;
  const int* src = eidx;
  const int* dst = eidx + E;

  char* ws = (char*)d_ws;
  size_t off = 0;
  auto alloc = [&](size_t bytes) {
    void* p = ws + off;
    off = (off + bytes + 255) & ~(size_t)255;
    return p;
  };
  unsigned short* xpb = (unsigned short*)alloc((size_t)Nn * HC * 2);
  float* a_srcv = (float*)alloc((size_t)Nn * NH * 4);
  float* a_dstv = (float*)alloc((size_t)Nn * NH * 4);
  float* a_rel  = (float*)alloc((size_t)R * NH * 4);
  int*   counts = (int*)alloc((size_t)Nn * 4);
  unsigned int* packed = (unsigned int*)alloc((size_t)Nn * SLOT * 4);

  const int GB = (Nn + 127) / 128;    // gemm blocks
  const int SB = 256;                 // scatter blocks (after gemm in dispatch order)

  hipMemsetAsync(counts, 0, (size_t)Nn * 4, stream);

  hipLaunchKernelGGL(fused_k, dim3(1 + GB + SB), dim3(512), 0, stream,
                     x, W, att_src, att_dst, rel_emb, W_edge, att_edge,
                     src, dst, etype, counts, packed,
                     xpb, a_srcv, a_dstv, a_rel, Nn, E, R, GB, SB);
  hipLaunchKernelGGL(gat_out_k, dim3((Nn + 3) / 4), dim3(256), 0, stream,
                     counts, packed, a_srcv, a_dstv, a_rel, R, xpb, bias, out, Nn);
}

// Round 13
// 135.765 us; speedup vs baseline: 1.0851x; 1.0341x over previous
//
#include <hip/hip_runtime.h>

#define IN_DIM 128
#define HC     256      // H*C
#define CCH    64
#define NH     4
#define NEG    0.2f
#define SLOT   64       // per-dst edge slot capacity (Poisson(16), max deg ~45)
#define NXCD   8

typedef __attribute__((ext_vector_type(4))) float f32x4;
typedef __attribute__((ext_vector_type(8))) short short8;

static __device__ __forceinline__ unsigned short f2bf(float f) {
  unsigned int u = __float_as_uint(f);
  u = (u + 0x7fffu + ((u >> 16) & 1u)) >> 16;   // RNE
  return (unsigned short)u;
}
static __device__ __forceinline__ float bf_lo(unsigned int u) {
  return __uint_as_float(u << 16);
}
static __device__ __forceinline__ float bf_hi(unsigned int u) {
  return __uint_as_float(u & 0xffff0000u);
}

// ---- K1: fused rel_attn (block 0) + gemm (1..GB) + XCD-partitioned scatter (rest) ----
__global__ __launch_bounds__(512) void fused_k(
    const float* __restrict__ x, const float* __restrict__ W,
    const float* __restrict__ att_src, const float* __restrict__ att_dst,
    const float* __restrict__ rel_emb, const float* __restrict__ W_edge,
    const float* __restrict__ att_edge,
    const int* __restrict__ src, const int* __restrict__ dst,
    const int* __restrict__ et, int* __restrict__ counts,
    unsigned int* __restrict__ packed,
    unsigned short* __restrict__ xpb, float* __restrict__ a_srcv,
    float* __restrict__ a_dstv, float* __restrict__ a_rel,
    int Nn, int E, int R, int GB, int SB) {
  __shared__ unsigned short Asm[128][136];  // 34.8 KB
  __shared__ unsigned short Bsm[64][136];   // 17.4 KB (reused as Xb[128][68] per head)
  const int bid = blockIdx.x;
  const int tid = threadIdx.x;

  if (bid == 0) {
    // rel_attn: a_rel[r,h] = rel_emb[r,:] . v[h,:], v[h,k]=sum_c ae[h,c]*W_edge[h*64+c,k]
    float* v = (float*)&Asm[0][0];  // 512 floats
    {
      int h = tid >> 7, k = tid & 127;
      const float* base = W_edge + (size_t)h * CCH * IN_DIM + k;
      const float* ae = att_edge + h * CCH;
      float s = 0.f;
#pragma unroll 8
      for (int c = 0; c < CCH; ++c) s += ae[c] * base[(size_t)c * IN_DIM];
      v[tid] = s;
    }
    __syncthreads();
    if (tid < R * NH) {
      int r = tid >> 2, h = tid & 3;
      const float4* re = (const float4*)(rel_emb + (size_t)r * IN_DIM);
      const float4* vv = (const float4*)(v + h * IN_DIM);
      float s = 0.f;
#pragma unroll 8
      for (int k = 0; k < IN_DIM / 4; ++k) {
        float4 a = re[k], b = vv[k];
        s += a.x * b.x + a.y * b.y + a.z * b.z + a.w * b.w;
      }
      a_rel[tid] = s;
    }
    return;
  }

  if (bid > GB) {
    // XCD-partitioned scatter: range = sb&7 rides round-robin block->XCD dispatch,
    // so each range's packed/counts slice stays in one XCD's L2 (kills the
    // 64B-line write amplification of random 4B stores).
    int sb = bid - GB - 1;          // 0..SB-1, SB % NXCD == 0
    int range = sb & (NXCD - 1);
    int grp = sb >> 3;              // group index within range
    int GPR = SB / NXCD;            // blocks per range
    int RS = (Nn + NXCD - 1) / NXCD;
    int lo = range * RS;
    int hi = lo + RS; if (hi > Nn) hi = Nn;
    for (int e = grp * 512 + tid; e < E; e += GPR * 512) {
      int d = dst[e];
      if (d < lo || d >= hi) continue;
      unsigned int pk = ((unsigned int)et[e] << 26) | (unsigned int)src[e];
      int pos = atomicAdd(&counts[d], 1);
      if (pos < SLOT) packed[(size_t)d * SLOT + pos] = pk;
    }
    return;
  }

  // ----- gemm: BM=128 rows, heads looped in-block, 8 waves
  const int bm = (bid - 1) * 128;
  {
    int row = tid >> 2, q = (tid & 3) * 32;
    int gm = bm + row;
    if (gm < Nn) {
      const float* xr = x + (size_t)gm * IN_DIM + q;
#pragma unroll
      for (int i = 0; i < 32; i += 8) {
        float4 a = *(const float4*)(xr + i);
        float4 b = *(const float4*)(xr + i + 4);
        ushort4 u0, u1;
        u0.x = f2bf(a.x); u0.y = f2bf(a.y); u0.z = f2bf(a.z); u0.w = f2bf(a.w);
        u1.x = f2bf(b.x); u1.y = f2bf(b.y); u1.z = f2bf(b.z); u1.w = f2bf(b.w);
        *(ushort4*)&Asm[row][q + i]     = u0;
        *(ushort4*)&Asm[row][q + i + 4] = u1;
      }
    } else {
      ushort4 zz = {0, 0, 0, 0};
#pragma unroll
      for (int i = 0; i < 32; i += 4) *(ushort4*)&Asm[row][q + i] = zz;
    }
  }

  const int wv = tid >> 6, lane = tid & 63;
  const int lr = lane & 15, lk = lane >> 4;
  unsigned short* Xb = (unsigned short*)&Bsm[0][0];   // [128][68] bf16 transpose buffer

  for (int h = 0; h < NH; ++h) {
    __syncthreads();   // prev head's Xb reads done (h=0: A staged)
    {
      int row = tid >> 3, q = (tid & 7) * 16;
      const float* wr = W + (size_t)(h * CCH + row) * IN_DIM + q;
#pragma unroll
      for (int i = 0; i < 16; i += 8) {
        float4 a = *(const float4*)(wr + i);
        float4 b = *(const float4*)(wr + i + 4);
        ushort4 u0, u1;
        u0.x = f2bf(a.x); u0.y = f2bf(a.y); u0.z = f2bf(a.z); u0.w = f2bf(a.w);
        u1.x = f2bf(b.x); u1.y = f2bf(b.y); u1.z = f2bf(b.z); u1.w = f2bf(b.w);
        *(ushort4*)&Bsm[row][q + i]     = u0;
        *(ushort4*)&Bsm[row][q + i + 4] = u1;
      }
    }
    __syncthreads();

    f32x4 acc[4] = {};
#pragma unroll
    for (int kk = 0; kk < 4; ++kk) {
      const int ko = kk * 32 + lk * 8;
      short8 af = *(const short8*)&Asm[wv * 16 + lr][ko];
      short8 b0 = *(const short8*)&Bsm[lr][ko];
      short8 b1 = *(const short8*)&Bsm[16 + lr][ko];
      short8 b2 = *(const short8*)&Bsm[32 + lr][ko];
      short8 b3 = *(const short8*)&Bsm[48 + lr][ko];
      acc[0] = __builtin_amdgcn_mfma_f32_16x16x32_bf16(af, b0, acc[0], 0, 0, 0);
      acc[1] = __builtin_amdgcn_mfma_f32_16x16x32_bf16(af, b1, acc[1], 0, 0, 0);
      acc[2] = __builtin_amdgcn_mfma_f32_16x16x32_bf16(af, b2, acc[2], 0, 0, 0);
      acc[3] = __builtin_amdgcn_mfma_f32_16x16x32_bf16(af, b3, acc[3], 0, 0, 0);
    }

    __syncthreads();   // all waves done reading Bsm (MFMA) -> safe to overwrite as Xb

    // transpose acc -> Xb[128][68] bf16
#pragma unroll
    for (int ni = 0; ni < 4; ++ni)
#pragma unroll
      for (int r = 0; r < 4; ++r)
        Xb[(wv * 16 + lk * 4 + r) * 68 + ni * 16 + lr] = f2bf(acc[ni][r]);

    // a_src/a_dst reduction (register-only, overlaps LDS latency)
    float as4[4], ad4[4];
#pragma unroll
    for (int ni = 0; ni < 4; ++ni) {
      as4[ni] = att_src[h * CCH + ni * 16 + lr];
      ad4[ni] = att_dst[h * CCH + ni * 16 + lr];
    }
#pragma unroll
    for (int r = 0; r < 4; ++r) {
      int gm = bm + wv * 16 + lk * 4 + r;
      float ps = 0.f, pd = 0.f;
#pragma unroll
      for (int ni = 0; ni < 4; ++ni) {
        ps += acc[ni][r] * as4[ni];
        pd += acc[ni][r] * ad4[ni];
      }
      ps += __shfl_xor(ps, 1); pd += __shfl_xor(pd, 1);
      ps += __shfl_xor(ps, 2); pd += __shfl_xor(pd, 2);
      ps += __shfl_xor(ps, 4); pd += __shfl_xor(pd, 4);
      ps += __shfl_xor(ps, 8); pd += __shfl_xor(pd, 8);
      if (lr == 0 && gm < Nn) {
        a_srcv[(size_t)gm * NH + h] = ps;
        a_dstv[(size_t)gm * NH + h] = pd;
      }
    }

    __syncthreads();   // transpose writes visible

    // coalesced xpb store: each thread stores one 16-col quarter-row (32 B)
    {
      int row = tid >> 2, q = tid & 3;
      int gm = bm + row;
      if (gm < Nn) {
        const unsigned int* xu = (const unsigned int*)(Xb + row * 68 + q * 16);
        uint4 o0, o1;
        o0.x = xu[0]; o0.y = xu[1]; o0.z = xu[2]; o0.w = xu[3];
        o1.x = xu[4]; o1.y = xu[5]; o1.z = xu[6]; o1.w = xu[7];
        uint4* dp = (uint4*)(xpb + (size_t)gm * HC + h * CCH + q * 16);
        dp[0] = o0; dp[1] = o1;
      }
    }
  }
}

// ---- K2: one wave per dst; 32 lanes x 16B per edge row, 2 edges/iter ----
__global__ void gat_out_k(const int* __restrict__ counts,
                          const unsigned int* __restrict__ packed,
                          const float* __restrict__ a_srcv, const float* __restrict__ a_dstv,
                          const float* __restrict__ a_rel, int R,
                          const unsigned short* __restrict__ xpb,
                          const float* __restrict__ bias,
                          float* __restrict__ out, int Nn) {
  __shared__ float arl[NH * 64];
  int tid = threadIdx.x;
  if (tid < R * NH) arl[tid] = a_rel[tid];
  __syncthreads();
  int d = blockIdx.x * 4 + (tid >> 6);
  if (d >= Nn) return;
  int lane = tid & 63;
  int half = lane >> 5, l32 = lane & 31;
  int hl = l32 >> 3;                 // head owned by this lane
  const int choff = l32 * 8;         // channels choff..choff+7 (global 0..255)
  int cnt = counts[d];
  if (cnt > SLOT) cnt = SLOT;
  int beg = d * SLOT, end = beg + cnt;
  float ad = a_dstv[(size_t)d * NH + hl];
  float z = 0.f;
  float acc[8] = {0.f, 0.f, 0.f, 0.f, 0.f, 0.f, 0.f, 0.f};

  int j = beg;
  for (; j + 4 <= end; j += 4) {
    unsigned int pkA = packed[j + half];
    unsigned int pkB = packed[j + 2 + half];
    int sA = (int)(pkA & 0x03FFFFFFu), tA = (int)(pkA >> 26);
    int sB = (int)(pkB & 0x03FFFFFFu), tB = (int)(pkB >> 26);
    float alA = a_srcv[(size_t)sA * NH + hl] + ad + arl[tA * NH + hl];
    float alB = a_srcv[(size_t)sB * NH + hl] + ad + arl[tB * NH + hl];
    uint4 uA = *(const uint4*)(xpb + (size_t)sA * HC + choff);
    uint4 uB = *(const uint4*)(xpb + (size_t)sB * HC + choff);
    alA = fmaxf(alA, NEG * alA);
    alB = fmaxf(alB, NEG * alB);
    float wA = __expf(alA), wB = __expf(alB);
    z += wA + wB;
    acc[0] += wA * bf_lo(uA.x) + wB * bf_lo(uB.x);
    acc[1] += wA * bf_hi(uA.x) + wB * bf_hi(uB.x);
    acc[2] += wA * bf_lo(uA.y) + wB * bf_lo(uB.y);
    acc[3] += wA * bf_hi(uA.y) + wB * bf_hi(uB.y);
    acc[4] += wA * bf_lo(uA.z) + wB * bf_lo(uB.z);
    acc[5] += wA * bf_hi(uA.z) + wB * bf_hi(uB.z);
    acc[6] += wA * bf_lo(uA.w) + wB * bf_lo(uB.w);
    acc[7] += wA * bf_hi(uA.w) + wB * bf_hi(uB.w);
  }
  for (; j < end; j += 2) {
    int e = j + half;
    bool valid = (e < end);
    int es = valid ? e : beg;
    unsigned int pk = packed[es];
    int s = (int)(pk & 0x03FFFFFFu), t = (int)(pk >> 26);
    float al = a_srcv[(size_t)s * NH + hl] + ad + arl[t * NH + hl];
    al = fmaxf(al, NEG * al);
    float w = valid ? __expf(al) : 0.f;
    uint4 u = *(const uint4*)(xpb + (size_t)s * HC + choff);
    z += w;
    acc[0] += w * bf_lo(u.x);
    acc[1] += w * bf_hi(u.x);
    acc[2] += w * bf_lo(u.y);
    acc[3] += w * bf_hi(u.y);
    acc[4] += w * bf_lo(u.z);
    acc[5] += w * bf_hi(u.z);
    acc[6] += w * bf_lo(u.w);
    acc[7] += w * bf_hi(u.w);
  }

  // combine the two halves (edge parity)
  z += __shfl_xor(z, 32);
#pragma unroll
  for (int q = 0; q < 8; ++q) acc[q] += __shfl_xor(acc[q], 32);
  float inv = 0.25f / (z + 1e-16f);
#pragma unroll
  for (int q = 0; q < 8; ++q) acc[q] *= inv;
  // head mean: sum lanes {l32, l32^8, l32^16, l32^24}
#pragma unroll
  for (int q = 0; q < 8; ++q) {
    acc[q] += __shfl_xor(acc[q], 8);
    acc[q] += __shfl_xor(acc[q], 16);
  }
  if (lane < 8) {
    int c0 = lane * 8;
    const float4 b0 = *(const float4*)(bias + c0);
    const float4 b1 = *(const float4*)(bias + c0 + 4);
    float4 o0, o1;
    o0.x = acc[0] + b0.x; o0.y = acc[1] + b0.y; o0.z = acc[2] + b0.z; o0.w = acc[3] + b0.w;
    o1.x = acc[4] + b1.x; o1.y = acc[5] + b1.y; o1.z = acc[6] + b1.z; o1.w = acc[7] + b1.w;
    *(float4*)(out + (size_t)d * CCH + c0) = o0;
    *(float4*)(out + (size_t)d * CCH + c0 + 4) = o1;
  }
}

extern "C" void kernel_launch(void* const* d_in, const int* in_sizes, int n_in,
                              void* d_out, int out_size, void* d_ws, size_t ws_size,
                              hipStream_t stream) {
  const float* x        = (const float*)d_in[0];
  const int*   eidx     = (const int*)d_in[1];
  const int*   etype    = (const int*)d_in[2];
  const float* rel_emb  = (const float*)d_in[3];
  const float* W        = (const float*)d_in[4];
  const float* att_src  = (const float*)d_in[5];
  const float* att_dst  = (const float*)d_in[6];
  const float* W_edge   = (const float*)d_in[7];
  const float* att_edge = (const float*)d_in[8];
  const float* bias     = (const float*)d_in[9];
  float* out = (float*)d_out;

  const int Nn = in_sizes[0] / IN_DIM;
  const int E  = in_sizes[1] / 2;
  const int R  = in_sizes[3] / IN_DIM;
  const int* src = eidx;
  const int* dst = eidx + E;

  char* ws = (char*)d_ws;
  size_t off = 0;
  auto alloc = [&](size_t bytes) {
    void* p = ws + off;
    off = (off + bytes + 255) & ~(size_t)255;
    return p;
  };
  unsigned short* xpb = (unsigned short*)alloc((size_t)Nn * HC * 2);
  float* a_srcv = (float*)alloc((size_t)Nn * NH * 4);
  float* a_dstv = (float*)alloc((size_t)Nn * NH * 4);
  float* a_rel  = (float*)alloc((size_t)R * NH * 4);
  int*   counts = (int*)alloc((size_t)Nn * 4);
  unsigned int* packed = (unsigned int*)alloc((size_t)Nn * SLOT * 4);

  const int GB = (Nn + 127) / 128;    // gemm blocks
  const int SB = 256;                 // scatter blocks (8 XCD-ranges x 32)

  hipMemsetAsync(counts, 0, (size_t)Nn * 4, stream);

  hipLaunchKernelGGL(fused_k, dim3(1 + GB + SB), dim3(512), 0, stream,
                     x, W, att_src, att_dst, rel_emb, W_edge, att_edge,
                     src, dst, etype, counts, packed,
                     xpb, a_srcv, a_dstv, a_rel, Nn, E, R, GB, SB);
  hipLaunchKernelGGL(gat_out_k, dim3((Nn + 3) / 4), dim3(256), 0, stream,
                     counts, packed, a_srcv, a_dstv, a_rel, R, xpb, bias, out, Nn);
}

// Round 14
// 120.637 us; speedup vs baseline: 1.2212x; 1.1254x over previous
//
#include <hip/hip_runtime.h>

#define IN_DIM 128
#define HC     256      // H*C
#define CCH    64
#define NH     4
#define NEG    0.2f
#define SLOT   64       // per-dst edge slot capacity (Poisson(16), max deg ~45)

typedef __attribute__((ext_vector_type(4))) float f32x4;
typedef __attribute__((ext_vector_type(8))) short short8;

static __device__ __forceinline__ unsigned short f2bf(float f) {
  unsigned int u = __float_as_uint(f);
  u = (u + 0x7fffu + ((u >> 16) & 1u)) >> 16;   // RNE
  return (unsigned short)u;
}
static __device__ __forceinline__ unsigned int pk2bf(float lo, float hi) {
  return (unsigned int)f2bf(lo) | ((unsigned int)f2bf(hi) << 16);
}
static __device__ __forceinline__ float bf_lo(unsigned int u) {
  return __uint_as_float(u << 16);
}
static __device__ __forceinline__ float bf_hi(unsigned int u) {
  return __uint_as_float(u & 0xffff0000u);
}

// ---- K1: fused rel_attn (block 0) + gemm (1..GB) + scatter (rest), 256 threads ----
// xpb uses PERMUTED channel order within each head: physical p = lk*16 + ni*4 + r
// corresponds to logical ch = ni*16 + lk*4 + r. gat_out un-permutes at the final write.
__global__ __launch_bounds__(256) void fused_k(
    const float* __restrict__ x, const float* __restrict__ W,
    const float* __restrict__ att_src, const float* __restrict__ att_dst,
    const float* __restrict__ rel_emb, const float* __restrict__ W_edge,
    const float* __restrict__ att_edge,
    const int* __restrict__ src, const int* __restrict__ dst,
    const int* __restrict__ et, int* __restrict__ counts,
    unsigned int* __restrict__ packed,
    unsigned short* __restrict__ xpb, float* __restrict__ a_srcv,
    float* __restrict__ a_dstv, float* __restrict__ a_rel,
    int Nn, int E, int R, int GB, int SB) {
  __shared__ unsigned short Asm[128][136];  // 34.8 KB
  __shared__ unsigned short Bsm[64][136];   // 17.4 KB
  const int bid = blockIdx.x;
  const int tid = threadIdx.x;

  if (bid == 0) {
    // rel_attn: a_rel[r,h] = rel_emb[r,:] . v[h,:], v[h,k]=sum_c ae[h,c]*W_edge[h*64+c,k]
    float* v = (float*)&Asm[0][0];  // 512 floats
    for (int t = tid; t < NH * IN_DIM; t += 256) {
      int h = t >> 7, k = t & 127;
      const float* base = W_edge + (size_t)h * CCH * IN_DIM + k;
      const float* ae = att_edge + h * CCH;
      float s = 0.f;
#pragma unroll 8
      for (int c = 0; c < CCH; ++c) s += ae[c] * base[(size_t)c * IN_DIM];
      v[t] = s;
    }
    __syncthreads();
    if (tid < R * NH) {
      int r = tid >> 2, h = tid & 3;
      const float4* re = (const float4*)(rel_emb + (size_t)r * IN_DIM);
      const float4* vv = (const float4*)(v + h * IN_DIM);
      float s = 0.f;
#pragma unroll 8
      for (int k = 0; k < IN_DIM / 4; ++k) {
        float4 a = re[k], b = vv[k];
        s += a.x * b.x + a.y * b.y + a.z * b.z + a.w * b.w;
      }
      a_rel[tid] = s;
    }
    return;
  }

  if (bid > GB) {
    // direct scatter: packed[d*SLOT + pos] = (etype<<26 | src)
    for (int e = (bid - GB - 1) * 256 + tid; e < E; e += SB * 256) {
      int d = dst[e];
      unsigned int pk = ((unsigned int)et[e] << 26) | (unsigned int)src[e];
      int pos = atomicAdd(&counts[d], 1);
      if (pos < SLOT) packed[(size_t)d * SLOT + pos] = pk;
    }
    return;
  }

  // ----- gemm: BM=128 rows, heads looped in-block, 4 waves
  const int bm = (bid - 1) * 128;
  {
    int row = tid >> 1, ch = (tid & 1) * 64;
    int gm = bm + row;
    if (gm < Nn) {
      const float* xr = x + (size_t)gm * IN_DIM + ch;
#pragma unroll
      for (int i = 0; i < 64; i += 8) {
        float4 a = *(const float4*)(xr + i);
        float4 b = *(const float4*)(xr + i + 4);
        ushort4 u0, u1;
        u0.x = f2bf(a.x); u0.y = f2bf(a.y); u0.z = f2bf(a.z); u0.w = f2bf(a.w);
        u1.x = f2bf(b.x); u1.y = f2bf(b.y); u1.z = f2bf(b.z); u1.w = f2bf(b.w);
        *(ushort4*)&Asm[row][ch + i]     = u0;
        *(ushort4*)&Asm[row][ch + i + 4] = u1;
      }
    } else {
      ushort4 zz = {0, 0, 0, 0};
#pragma unroll
      for (int i = 0; i < 64; i += 4) *(ushort4*)&Asm[row][ch + i] = zz;
    }
  }

  const int wv = tid >> 6, lane = tid & 63;
  const int lr = lane & 15, lk = lane >> 4;

  for (int h = 0; h < NH; ++h) {
    __syncthreads();   // prev head's Bsm reads done (h=0: A staged)
    if (tid < 128) {
      int row = tid >> 1, ch = (tid & 1) * 64;
      const float* wr = W + (size_t)(h * CCH + row) * IN_DIM + ch;
#pragma unroll
      for (int i = 0; i < 64; i += 8) {
        float4 a = *(const float4*)(wr + i);
        float4 b = *(const float4*)(wr + i + 4);
        ushort4 u0, u1;
        u0.x = f2bf(a.x); u0.y = f2bf(a.y); u0.z = f2bf(a.z); u0.w = f2bf(a.w);
        u1.x = f2bf(b.x); u1.y = f2bf(b.y); u1.z = f2bf(b.z); u1.w = f2bf(b.w);
        *(ushort4*)&Bsm[row][ch + i]     = u0;
        *(ushort4*)&Bsm[row][ch + i + 4] = u1;
      }
    }
    __syncthreads();

    // swapped-operand MFMA: acc[mi][ni] = W_group_ni x x_rows_mi -> lane holds
    // one row (lr) x channels {ni*16 + lk*4 + r}
    f32x4 acc[2][4] = {};
#pragma unroll
    for (int kk = 0; kk < 4; ++kk) {
      const int ko = kk * 32 + lk * 8;
      short8 af0 = *(const short8*)&Asm[wv * 32 + lr][ko];
      short8 af1 = *(const short8*)&Asm[wv * 32 + 16 + lr][ko];
      short8 bf0 = *(const short8*)&Bsm[lr][ko];
      short8 bf1 = *(const short8*)&Bsm[16 + lr][ko];
      short8 bf2v = *(const short8*)&Bsm[32 + lr][ko];
      short8 bf3 = *(const short8*)&Bsm[48 + lr][ko];
      acc[0][0] = __builtin_amdgcn_mfma_f32_16x16x32_bf16(bf0, af0, acc[0][0], 0, 0, 0);
      acc[0][1] = __builtin_amdgcn_mfma_f32_16x16x32_bf16(bf1, af0, acc[0][1], 0, 0, 0);
      acc[0][2] = __builtin_amdgcn_mfma_f32_16x16x32_bf16(bf2v, af0, acc[0][2], 0, 0, 0);
      acc[0][3] = __builtin_amdgcn_mfma_f32_16x16x32_bf16(bf3, af0, acc[0][3], 0, 0, 0);
      acc[1][0] = __builtin_amdgcn_mfma_f32_16x16x32_bf16(bf0, af1, acc[1][0], 0, 0, 0);
      acc[1][1] = __builtin_amdgcn_mfma_f32_16x16x32_bf16(bf1, af1, acc[1][1], 0, 0, 0);
      acc[1][2] = __builtin_amdgcn_mfma_f32_16x16x32_bf16(bf2v, af1, acc[1][2], 0, 0, 0);
      acc[1][3] = __builtin_amdgcn_mfma_f32_16x16x32_bf16(bf3, af1, acc[1][3], 0, 0, 0);
    }

    // att vectors for this lane's channels: logical ch = ni*16 + lk*4 + r
    float4 asv[4], adv[4];
#pragma unroll
    for (int ni = 0; ni < 4; ++ni) {
      asv[ni] = *(const float4*)(att_src + h * CCH + ni * 16 + lk * 4);
      adv[ni] = *(const float4*)(att_dst + h * CCH + ni * 16 + lk * 4);
    }

#pragma unroll
    for (int mi = 0; mi < 2; ++mi) {
      int gm = bm + wv * 32 + mi * 16 + lr;
      bool ok = (gm < Nn);
      // direct xpb store, permuted channel order: p = lk*16 + ni*4 + r
      if (ok) {
        unsigned short* xb = xpb + (size_t)gm * HC + h * CCH + lk * 16;
        uint4 o0, o1;
        o0.x = pk2bf(acc[mi][0][0], acc[mi][0][1]);
        o0.y = pk2bf(acc[mi][0][2], acc[mi][0][3]);
        o0.z = pk2bf(acc[mi][1][0], acc[mi][1][1]);
        o0.w = pk2bf(acc[mi][1][2], acc[mi][1][3]);
        o1.x = pk2bf(acc[mi][2][0], acc[mi][2][1]);
        o1.y = pk2bf(acc[mi][2][2], acc[mi][2][3]);
        o1.z = pk2bf(acc[mi][3][0], acc[mi][3][1]);
        o1.w = pk2bf(acc[mi][3][2], acc[mi][3][3]);
        ((uint4*)xb)[0] = o0;
        ((uint4*)xb)[1] = o1;
      }
      // a_src/a_dst: dot over this lane's 16 channels, reduce across lk groups
      float ps = 0.f, pd = 0.f;
#pragma unroll
      for (int ni = 0; ni < 4; ++ni) {
        ps += acc[mi][ni][0] * asv[ni].x + acc[mi][ni][1] * asv[ni].y +
              acc[mi][ni][2] * asv[ni].z + acc[mi][ni][3] * asv[ni].w;
        pd += acc[mi][ni][0] * adv[ni].x + acc[mi][ni][1] * adv[ni].y +
              acc[mi][ni][2] * adv[ni].z + acc[mi][ni][3] * adv[ni].w;
      }
      ps += __shfl_xor(ps, 16); pd += __shfl_xor(pd, 16);
      ps += __shfl_xor(ps, 32); pd += __shfl_xor(pd, 32);
      if (lane < 16 && ok) {
        a_srcv[(size_t)gm * NH + h] = ps;
        a_dstv[(size_t)gm * NH + h] = pd;
      }
    }
  }
}

// ---- K2: one wave per dst; 32 lanes x 16B per edge row, 2 edges/iter ----
__global__ void gat_out_k(const int* __restrict__ counts,
                          const unsigned int* __restrict__ packed,
                          const float* __restrict__ a_srcv, const float* __restrict__ a_dstv,
                          const float* __restrict__ a_rel, int R,
                          const unsigned short* __restrict__ xpb,
                          const float* __restrict__ bias,
                          float* __restrict__ out, int Nn) {
  __shared__ float arl[NH * 64];
  int tid = threadIdx.x;
  if (tid < R * NH) arl[tid] = a_rel[tid];
  __syncthreads();
  int d = blockIdx.x * 4 + (tid >> 6);
  if (d >= Nn) return;
  int lane = tid & 63;
  int half = lane >> 5, l32 = lane & 31;
  int hl = l32 >> 3;                 // head owned by this lane
  const int choff = l32 * 8;         // PHYSICAL channels choff..choff+7 (0..255)
  int cnt = counts[d];
  if (cnt > SLOT) cnt = SLOT;
  int beg = d * SLOT, end = beg + cnt;
  float ad = a_dstv[(size_t)d * NH + hl];
  float z = 0.f;
  float acc[8] = {0.f, 0.f, 0.f, 0.f, 0.f, 0.f, 0.f, 0.f};

  int j = beg;
  for (; j + 4 <= end; j += 4) {
    unsigned int pkA = packed[j + half];
    unsigned int pkB = packed[j + 2 + half];
    int sA = (int)(pkA & 0x03FFFFFFu), tA = (int)(pkA >> 26);
    int sB = (int)(pkB & 0x03FFFFFFu), tB = (int)(pkB >> 26);
    float alA = a_srcv[(size_t)sA * NH + hl] + ad + arl[tA * NH + hl];
    float alB = a_srcv[(size_t)sB * NH + hl] + ad + arl[tB * NH + hl];
    uint4 uA = *(const uint4*)(xpb + (size_t)sA * HC + choff);
    uint4 uB = *(const uint4*)(xpb + (size_t)sB * HC + choff);
    alA = fmaxf(alA, NEG * alA);
    alB = fmaxf(alB, NEG * alB);
    float wA = __expf(alA), wB = __expf(alB);
    z += wA + wB;
    acc[0] += wA * bf_lo(uA.x) + wB * bf_lo(uB.x);
    acc[1] += wA * bf_hi(uA.x) + wB * bf_hi(uB.x);
    acc[2] += wA * bf_lo(uA.y) + wB * bf_lo(uB.y);
    acc[3] += wA * bf_hi(uA.y) + wB * bf_hi(uB.y);
    acc[4] += wA * bf_lo(uA.z) + wB * bf_lo(uB.z);
    acc[5] += wA * bf_hi(uA.z) + wB * bf_hi(uB.z);
    acc[6] += wA * bf_lo(uA.w) + wB * bf_lo(uB.w);
    acc[7] += wA * bf_hi(uA.w) + wB * bf_hi(uB.w);
  }
  for (; j < end; j += 2) {
    int e = j + half;
    bool valid = (e < end);
    int es = valid ? e : beg;
    unsigned int pk = packed[es];
    int s = (int)(pk & 0x03FFFFFFu), t = (int)(pk >> 26);
    float al = a_srcv[(size_t)s * NH + hl] + ad + arl[t * NH + hl];
    al = fmaxf(al, NEG * al);
    float w = valid ? __expf(al) : 0.f;
    uint4 u = *(const uint4*)(xpb + (size_t)s * HC + choff);
    z += w;
    acc[0] += w * bf_lo(u.x);
    acc[1] += w * bf_hi(u.x);
    acc[2] += w * bf_lo(u.y);
    acc[3] += w * bf_hi(u.y);
    acc[4] += w * bf_lo(u.z);
    acc[5] += w * bf_hi(u.z);
    acc[6] += w * bf_lo(u.w);
    acc[7] += w * bf_hi(u.w);
  }

  // combine the two halves (edge parity)
  z += __shfl_xor(z, 32);
#pragma unroll
  for (int q = 0; q < 8; ++q) acc[q] += __shfl_xor(acc[q], 32);
  float inv = 0.25f / (z + 1e-16f);
#pragma unroll
  for (int q = 0; q < 8; ++q) acc[q] *= inv;
  // head mean: sum lanes {l32, l32^8, l32^16, l32^24} (same physical offset, diff head)
#pragma unroll
  for (int q = 0; q < 8; ++q) {
    acc[q] += __shfl_xor(acc[q], 8);
    acc[q] += __shfl_xor(acc[q], 16);
  }
  if (lane < 8) {
    // un-permute: physical p = lane*8+q -> logical ch = ((p>>2)&3)*16 + (p>>4)*4 + (p&3)
#pragma unroll
    for (int q = 0; q < 8; ++q) {
      int p = lane * 8 + q;
      int ch = ((p >> 2) & 3) * 16 + (p >> 4) * 4 + (p & 3);
      out[(size_t)d * CCH + ch] = acc[q] + bias[ch];
    }
  }
}

extern "C" void kernel_launch(void* const* d_in, const int* in_sizes, int n_in,
                              void* d_out, int out_size, void* d_ws, size_t ws_size,
                              hipStream_t stream) {
  const float* x        = (const float*)d_in[0];
  const int*   eidx     = (const int*)d_in[1];
  const int*   etype    = (const int*)d_in[2];
  const float* rel_emb  = (const float*)d_in[3];
  const float* W        = (const float*)d_in[4];
  const float* att_src  = (const float*)d_in[5];
  const float* att_dst  = (const float*)d_in[6];
  const float* W_edge   = (const float*)d_in[7];
  const float* att_edge = (const float*)d_in[8];
  const float* bias     = (const float*)d_in[9];
  float* out = (float*)d_out;

  const int Nn = in_sizes[0] / IN_DIM;
  const int E  = in_sizes[1] / 2;
  const int R  = in_sizes[3] / IN_DIM;
  const int* src = eidx;
  const int* dst = eidx + E;

  char* ws = (char*)d_ws;
  size_t off = 0;
  auto alloc = [&](size_t bytes) {
    void* p = ws + off;
    off = (off + bytes + 255) & ~(size_t)255;
    return p;
  };
  unsigned short* xpb = (unsigned short*)alloc((size_t)Nn * HC * 2);
  float* a_srcv = (float*)alloc((size_t)Nn * NH * 4);
  float* a_dstv = (float*)alloc((size_t)Nn * NH * 4);
  float* a_rel  = (float*)alloc((size_t)R * NH * 4);
  int*   counts = (int*)alloc((size_t)Nn * 4);
  unsigned int* packed = (unsigned int*)alloc((size_t)Nn * SLOT * 4);

  const int GB = (Nn + 127) / 128;    // gemm blocks
  const int SB = 384;                 // scatter blocks (after gemm in dispatch order)

  hipMemsetAsync(counts, 0, (size_t)Nn * 4, stream);

  hipLaunchKernelGGL(fused_k, dim3(1 + GB + SB), dim3(256), 0, stream,
                     x, W, att_src, att_dst, rel_emb, W_edge, att_edge,
                     src, dst, etype, counts, packed,
                     xpb, a_srcv, a_dstv, a_rel, Nn, E, R, GB, SB);
  hipLaunchKernelGGL(gat_out_k, dim3((Nn + 3) / 4), dim3(256), 0, stream,
                     counts, packed, a_srcv, a_dstv, a_rel, R, xpb, bias, out, Nn);
}